// Round 5
// baseline (326.213 us; speedup 1.0000x reference)
//
#include <hip/hip_runtime.h>
#include <hip/hip_bf16.h>

// B=4, S=2048, D=1024 attention. bf16 MFMA, fp32 accum.
// Round 5: 8-phase 256x256 GEMM (T3+T4 counted vmcnt + T5 setprio), fused QKV proj.
//
// ws layout (bytes):
//   xb   @ 0         : bf16 [8192][1024]
//   wt   @ 16777216  : bf16 [3][1024][1024]  ([n][k], order k,q,v) == [3072][1024]
//   kb   @ 23068672  : bf16 [4][2048][1024]
//   qb   @ 39845888  : bf16 [4][2048][1024]
//   vtb  @ 56623104  : bf16 [4][1024][2048]  (per-batch transposed V)
//   sc   @ 73400320  : bf16 [4][2048][2048]  (scores, softmaxed in place)

typedef __attribute__((ext_vector_type(8))) short short8;
typedef __attribute__((ext_vector_type(4))) float f32x4;

__device__ __forceinline__ unsigned short f2b(float f) {
    unsigned u = __builtin_bit_cast(unsigned, f);
    unsigned r = 0x7FFFu + ((u >> 16) & 1u);
    return (unsigned short)((u + r) >> 16);
}
__device__ __forceinline__ float b2f(unsigned short h) {
    return __builtin_bit_cast(float, ((unsigned)h) << 16);
}

__device__ __forceinline__ void gload16(const void* g, void* lds_uniform_base) {
    __builtin_amdgcn_global_load_lds(
        (const __attribute__((address_space(1))) unsigned int*)(unsigned long long)g,
        (__attribute__((address_space(3))) unsigned int*)(unsigned)(unsigned long long)lds_uniform_base,
        16, 0, 0);
}

#define BARRIER __builtin_amdgcn_s_barrier()
#define WAIT_LGKM0 do { asm volatile("s_waitcnt lgkmcnt(0)" ::: "memory"); __builtin_amdgcn_sched_barrier(0); } while (0)
#define WAIT_VM(n) do { asm volatile("s_waitcnt vmcnt(" #n ")" ::: "memory"); __builtin_amdgcn_sched_barrier(0); } while (0)

__global__ void cvt_x(const float* __restrict__ x, unsigned short* __restrict__ xb) {
    int i = blockIdx.x * 256 + threadIdx.x;
    float4 v = ((const float4*)x)[i];
    ushort4 o;
    o.x = f2b(v.x); o.y = f2b(v.y); o.z = f2b(v.z); o.w = f2b(v.w);
    ((ushort4*)xb)[i] = o;
}

__global__ void transpose_w(const float* __restrict__ w0, const float* __restrict__ w1,
                            const float* __restrict__ w2, unsigned short* __restrict__ wt) {
    const float* W = (blockIdx.z == 0) ? w0 : (blockIdx.z == 1) ? w1 : w2;
    __shared__ float t[32][33];
    int k0 = blockIdx.y * 32, n0 = blockIdx.x * 32;
    int tx = threadIdx.x, ty = threadIdx.y; // (32,8)
#pragma unroll
    for (int i = 0; i < 4; i++)
        t[ty * 4 + i][tx] = W[(size_t)(k0 + ty * 4 + i) * 1024 + n0 + tx];
    __syncthreads();
    unsigned short* out = wt + (size_t)blockIdx.z * 1024 * 1024;
#pragma unroll
    for (int i = 0; i < 4; i++)
        out[(size_t)(n0 + ty * 4 + i) * 1024 + k0 + tx] = f2b(t[tx][ty * 4 + i]);
}

// ---------------------------------------------------------------------------
// 8-phase 256x256 NT GEMM. A [M][K], B [N][K] bf16; C = alpha*A.B^T + bias.
// 8 waves (2m x 4n), per-wave out 128x64 = acc[8][4] frags.
// LDS: As/Bs[2 buf][256 rows][64 k] linear; chunk = 64 rows = 8KB = 1 gload/thread.
//
// Phase ledger (iteration computes tile t in buf0 [ph1-4], t+1 in buf1 [ph5-8];
// quadrant (mh,nh); A-half regs live 2 phases, B-half regs live 3 phases so each
// LDS row is ds_read exactly once per tile):
//   chip-wide last ds_read:  buf0.As c0,c2: ph1   c1,c3: ph3   buf0.Bs all: ph2
//                            buf1.As c0,c2: ph5   c1,c3: ph7   buf1.Bs all: ph6
//   stage slots (2 gloads each, region provably free by prior phase's closing barrier):
//     ph1: buf1.Bs c2,c3 <- (t+1)   ph2: buf0.As c0,c2 <- (t+2)
//     ph3: buf0.Bs c0,c1 <- (t+2)   ph4: buf0.As c1,c3 <- (t+2)  + vmcnt
//     ph5: buf0.Bs c2,c3 <- (t+2)   ph6: buf1.As c0,c2 <- (t+3)
//     ph7: buf1.Bs c0,c1 <- (t+3)   ph8: buf1.As c1,c3 <- (t+3)  + vmcnt
//   vmcnt(6) at ph4: leaves ph2,3,4 in flight => tile t+1 fully landed for ph5-8.
//   vmcnt(6) at ph8: leaves ph6,7,8 in flight => tile t+2 fully landed for next ph1-4.
//   Final iteration: prefetch guards (tt>=nt) off => must drain with vmcnt(0),
//   since counted-6 would under-wait with fewer outstanding.
// MODE 0: bf16 [m][n] +z*sC. MODE 2: fp32 [m][n] +z*sC.
// MODE 3: fused proj, N=3072: col<1024 -> C0(kb), <2048 -> C1(qb), else C2(vtb transposed).
// ---------------------------------------------------------------------------
template <int MODE>
__global__ __launch_bounds__(512, 2) void gemm8(
    const unsigned short* __restrict__ A, const unsigned short* __restrict__ Bm,
    void* __restrict__ C0, void* __restrict__ C1, void* __restrict__ C2,
    const float* __restrict__ bias0, const float* __restrict__ bias1,
    const float* __restrict__ bias2,
    int N, int K, long long sA, long long sB, long long sC, float alpha) {
    __shared__ unsigned short As[2][256 * 64];
    __shared__ unsigned short Bs[2][256 * 64];
    const int tid = threadIdx.x;
    const int wave = tid >> 6, lane = tid & 63;

    // T1 bijective XCD swizzle (m204)
    const int gx = gridDim.x, gy = gridDim.y;
    const int nwg = gx * gy * (int)gridDim.z;
    const int orig = blockIdx.x + gx * (blockIdx.y + gy * blockIdx.z);
    const int q8 = nwg >> 3, r8 = nwg & 7;
    const int xcd = orig & 7, sub = orig >> 3;
    const int wg = (xcd < r8 ? xcd * (q8 + 1) : r8 * (q8 + 1) + (xcd - r8) * q8) + sub;
    const int bx = wg % gx;
    const int tmp = wg / gx;
    const int by = tmp % gy, bz = tmp / gy;

    const int m0 = by * 256, n0 = bx * 256;
    A += (long long)bz * sA;
    Bm += (long long)bz * sB;

    const int wm = wave >> 2, wn = wave & 3; // 2m x 4n waves
    const int l16 = lane & 15;
    const int lk = (lane >> 4) << 3;
    const int nt = K >> 6; // 64-wide K tiles (nt even, >= 4)

    f32x4 acc[8][4];
#pragma unroll
    for (int m = 0; m < 8; m++)
#pragma unroll
        for (int n = 0; n < 4; n++) acc[m][n] = (f32x4){0.f, 0.f, 0.f, 0.f};

    const int strow = tid >> 3;        // staging row within 64-row chunk
    const int stkk = (tid & 7) << 3;   // staging k offset (bf16)

    auto ST_A = [&](int bb, int c, int tt) {
        if (tt >= nt) return;
        gload16(A + (size_t)(m0 + c * 64 + strow) * K + (tt << 6) + stkk,
                (char*)&As[bb][0] + c * 8192 + wave * 1024);
    };
    auto ST_B = [&](int bb, int c, int tt) {
        if (tt >= nt) return;
        gload16(Bm + (size_t)(n0 + c * 64 + strow) * K + (tt << 6) + stkk,
                (char*)&Bs[bb][0] + c * 8192 + wave * 1024);
    };

    short8 af[4][2], bf0[2][2], bf1[2][2];
    auto DS_A = [&](int bb, int mh) { // 8 ds_read_b128
#pragma unroll
        for (int fm = 0; fm < 4; fm++)
#pragma unroll
            for (int ks = 0; ks < 2; ks++)
                af[fm][ks] = *(const short8*)
                    &As[bb][(wm * 128 + mh * 64 + fm * 16 + l16) * 64 + ks * 32 + lk];
    };
    auto DS_B = [&](int bb, int nh, short8 (&bf)[2][2]) { // 4 ds_read_b128
#pragma unroll
        for (int fn = 0; fn < 2; fn++)
#pragma unroll
            for (int ks = 0; ks < 2; ks++)
                bf[fn][ks] = *(const short8*)
                    &Bs[bb][(wn * 64 + nh * 32 + fn * 16 + l16) * 64 + ks * 32 + lk];
    };
    auto MFMA16 = [&](int mh, int nh, short8 (&bf)[2][2]) {
        __builtin_amdgcn_s_setprio(1);
#pragma unroll
        for (int fm = 0; fm < 4; fm++)
#pragma unroll
            for (int fn = 0; fn < 2; fn++)
#pragma unroll
                for (int ks = 0; ks < 2; ks++)
                    acc[mh * 4 + fm][nh * 2 + fn] = __builtin_amdgcn_mfma_f32_16x16x32_bf16(
                        af[fm][ks], bf[fn][ks], acc[mh * 4 + fm][nh * 2 + fn], 0, 0, 0);
        __builtin_amdgcn_s_setprio(0);
    };

    // prologue: tile0 full (8), tile1 As c0-c3 + Bs c0,c1 (6); tile1 Bs c2,c3 comes at ph1
    ST_A(0, 0, 0); ST_A(0, 1, 0); ST_A(0, 2, 0); ST_A(0, 3, 0);
    ST_B(0, 0, 0); ST_B(0, 1, 0); ST_B(0, 2, 0); ST_B(0, 3, 0);
    ST_A(1, 0, 1); ST_A(1, 1, 1); ST_A(1, 2, 1); ST_A(1, 3, 1);
    ST_B(1, 0, 1); ST_B(1, 1, 1);
    WAIT_VM(6); // tile0's 8 are the oldest; drains them, leaves tile1's 6 in flight
    BARRIER;

    for (int it = 0; it < (nt >> 1); ++it) {
        const int t = it << 1;
        const bool last = (t + 2 >= nt);
        // ph1
        DS_A(0, 0); DS_B(0, 0, bf0);
        ST_B(1, 2, t + 1); ST_B(1, 3, t + 1);
        BARRIER; WAIT_LGKM0;
        MFMA16(0, 0, bf0);
        BARRIER;
        // ph2
        DS_B(0, 1, bf1);
        ST_A(0, 0, t + 2); ST_A(0, 2, t + 2);
        BARRIER; WAIT_LGKM0;
        MFMA16(0, 1, bf1);
        BARRIER;
        // ph3
        DS_A(0, 1);
        ST_B(0, 0, t + 2); ST_B(0, 1, t + 2);
        BARRIER; WAIT_LGKM0;
        MFMA16(1, 0, bf0);
        BARRIER;
        // ph4 (no ds_reads; counted vmcnt releases ph5's reads of tile t+1)
        ST_A(0, 1, t + 2); ST_A(0, 3, t + 2);
        BARRIER;
        MFMA16(1, 1, bf1);
        if (last) { WAIT_VM(0); } else { WAIT_VM(6); }
        BARRIER;
        // ph5
        DS_A(1, 0); DS_B(1, 0, bf0);
        ST_B(0, 2, t + 2); ST_B(0, 3, t + 2);
        BARRIER; WAIT_LGKM0;
        MFMA16(0, 0, bf0);
        BARRIER;
        // ph6
        DS_B(1, 1, bf1);
        ST_A(1, 0, t + 3); ST_A(1, 2, t + 3);
        BARRIER; WAIT_LGKM0;
        MFMA16(0, 1, bf1);
        BARRIER;
        // ph7
        DS_A(1, 1);
        ST_B(1, 0, t + 3); ST_B(1, 1, t + 3);
        BARRIER; WAIT_LGKM0;
        MFMA16(1, 0, bf0);
        BARRIER;
        // ph8 (counted vmcnt releases next-iter ph1's reads of tile t+2)
        ST_A(1, 1, t + 3); ST_A(1, 3, t + 3);
        BARRIER;
        MFMA16(1, 1, bf1);
        if (last) { WAIT_VM(0); } else { WAIT_VM(6); }
        BARRIER;
    }

    const int rowb0 = m0 + wm * 128 + ((lane >> 4) << 2);
#pragma unroll
    for (int m = 0; m < 8; m++) {
#pragma unroll
        for (int n = 0; n < 4; n++) {
            const int row = rowb0 + m * 16;
            const int col = n0 + wn * 64 + n * 16 + l16;
            if (MODE == 0) {
                unsigned short* C = (unsigned short*)C0 + (long long)bz * sC;
                float bb = bias0 ? bias0[col] : 0.f;
#pragma unroll
                for (int i = 0; i < 4; i++)
                    C[(size_t)(row + i) * N + col] = f2b(acc[m][n][i] * alpha + bb);
            } else if (MODE == 2) {
                float* C = (float*)C0 + (long long)bz * sC;
                float bb = bias0 ? bias0[col] : 0.f;
#pragma unroll
                for (int i = 0; i < 4; i++)
                    C[(size_t)(row + i) * N + col] = acc[m][n][i] * alpha + bb;
            } else { // MODE 3: fused proj routing (block-uniform sel)
                const int sel = col >> 10, lc = col & 1023;
                const float bb = (sel == 0 ? bias0 : sel == 1 ? bias1 : bias2)[lc];
                if (sel < 2) {
                    unsigned short* C = (unsigned short*)(sel == 0 ? C0 : C1);
#pragma unroll
                    for (int i = 0; i < 4; i++)
                        C[(size_t)(row + i) * 1024 + lc] = f2b(acc[m][n][i] + bb);
                } else {
                    const int b = row >> 11, s = row & 2047; // 4 consecutive s
                    ushort4 pk;
                    pk.x = f2b(acc[m][n][0] + bb);
                    pk.y = f2b(acc[m][n][1] + bb);
                    pk.z = f2b(acc[m][n][2] + bb);
                    pk.w = f2b(acc[m][n][3] + bb);
                    *(ushort4*)((unsigned short*)C2 + (size_t)b * 2097152 +
                                (size_t)lc * 2048 + s) = pk;
                }
            }
        }
    }
}

// in-place row softmax: sc bf16 [8192][2048], fp32 math
__global__ __launch_bounds__(256) void softmax_inplace(unsigned short* __restrict__ sc) {
    const size_t row = blockIdx.x;
    unsigned short* p = sc + row * 2048;
    const int tid = threadIdx.x;
    const int wave = tid >> 6, lane = tid & 63;
    short8 raw = *(const short8*)&p[tid * 8];
    float f[8];
#pragma unroll
    for (int i = 0; i < 8; i++) f[i] = b2f((unsigned short)raw[i]);
    float mx = f[0];
#pragma unroll
    for (int i = 1; i < 8; i++) mx = fmaxf(mx, f[i]);
#pragma unroll
    for (int o = 32; o > 0; o >>= 1) mx = fmaxf(mx, __shfl_xor(mx, o, 64));
    __shared__ float red[8];
    if (lane == 0) red[wave] = mx;
    __syncthreads();
    mx = fmaxf(fmaxf(red[0], red[1]), fmaxf(red[2], red[3]));
    float e[8], s = 0.f;
#pragma unroll
    for (int i = 0; i < 8; i++) { e[i] = __expf(f[i] - mx); s += e[i]; }
#pragma unroll
    for (int o = 32; o > 0; o >>= 1) s += __shfl_xor(s, o, 64);
    if (lane == 0) red[4 + wave] = s;
    __syncthreads();
    s = (red[4] + red[5]) + (red[6] + red[7]);
    float r = 1.0f / s;
    short8 outv;
#pragma unroll
    for (int i = 0; i < 8; i++) outv[i] = (short)f2b(e[i] * r);
    *(short8*)&p[tid * 8] = outv;
}

extern "C" void kernel_launch(void* const* d_in, const int* in_sizes, int n_in,
                              void* d_out, int out_size, void* d_ws, size_t ws_size,
                              hipStream_t stream) {
    const float* x  = (const float*)d_in[0];
    const float* Wk = (const float*)d_in[1];
    const float* bk = (const float*)d_in[2];
    const float* Wq = (const float*)d_in[3];
    const float* bq = (const float*)d_in[4];
    const float* Wv = (const float*)d_in[5];
    const float* bv = (const float*)d_in[6];
    float* out = (float*)d_out;

    char* ws = (char*)d_ws;
    unsigned short* xb  = (unsigned short*)(ws);
    unsigned short* wt  = (unsigned short*)(ws + 16777216);
    unsigned short* kb  = (unsigned short*)(ws + 23068672);
    unsigned short* qb  = (unsigned short*)(ws + 39845888);
    unsigned short* vtb = (unsigned short*)(ws + 56623104);
    unsigned short* sc  = (unsigned short*)(ws + 73400320);

    cvt_x<<<8192, 256, 0, stream>>>(x, xb);
    transpose_w<<<dim3(32, 32, 3), dim3(32, 8), 0, stream>>>(Wk, Wq, Wv, wt);

    // fused QKV projection: M=8192, N=3072, K=1024 — grid 12x32 = 384 blocks
    gemm8<3><<<dim3(12, 32, 1), 512, 0, stream>>>(
        xb, wt, kb, qb, vtb, bk, bq, bv, 3072, 1024, 0, 0, 0, 1.f);

    // scores: per batch 2048x2048, K=1024 — grid 8x8x4 = 256 blocks
    gemm8<0><<<dim3(8, 8, 4), 512, 0, stream>>>(
        qb, kb, sc, nullptr, nullptr, nullptr, nullptr, nullptr,
        2048, 1024, 2048LL * 1024, 2048LL * 1024, 2048LL * 2048, 0.03125f);

    softmax_inplace<<<8192, 256, 0, stream>>>(sc);

    // PV: per batch M=2048, N=1024, K=2048 — grid 4x8x4 = 128 blocks
    gemm8<2><<<dim3(4, 8, 4), 512, 0, stream>>>(
        sc, vtb, out, nullptr, nullptr, nullptr, nullptr, nullptr,
        1024, 2048, 2048LL * 2048, 1024LL * 2048, 2048LL * 1024, 1.f);
}

// Round 9
// 266.594 us; speedup vs baseline: 1.2236x; 1.2236x over previous
//
#include <hip/hip_runtime.h>
#include <hip/hip_bf16.h>

// B=4, S=2048, D=1024 attention. bf16 MFMA, fp32 accum.
// Round 6: gemm8 = 8-phase 256x256 (T3+T4 counted vmcnt, T5 setprio) + T2-analog
// both-sides LDS swizzle (rule 21: linear gload_lds dest, inverse-permuted global
// source, swizzled ds_read). Bare asm waits per m201 template (no sched_barrier pins).
// PV uses the proven 2-phase gemm2. Proj stays fused (single N=3072 dispatch).
//
// ws layout (bytes):
//   xb   @ 0         : bf16 [8192][1024]
//   wt   @ 16777216  : bf16 [3][1024][1024]  ([n][k], order k,q,v) == [3072][1024]
//   kb   @ 23068672  : bf16 [4][2048][1024]
//   qb   @ 39845888  : bf16 [4][2048][1024]
//   vtb  @ 56623104  : bf16 [4][1024][2048]  (per-batch transposed V)
//   sc   @ 73400320  : bf16 [4][2048][2048]  (scores, softmaxed in place)

typedef __attribute__((ext_vector_type(8))) short short8;
typedef __attribute__((ext_vector_type(4))) float f32x4;

__device__ __forceinline__ unsigned short f2b(float f) {
    unsigned u = __builtin_bit_cast(unsigned, f);
    unsigned r = 0x7FFFu + ((u >> 16) & 1u);
    return (unsigned short)((u + r) >> 16);
}
__device__ __forceinline__ float b2f(unsigned short h) {
    return __builtin_bit_cast(float, ((unsigned)h) << 16);
}

__device__ __forceinline__ void gload16(const void* g, void* lds_uniform_base) {
    __builtin_amdgcn_global_load_lds(
        (const __attribute__((address_space(1))) unsigned int*)(unsigned long long)g,
        (__attribute__((address_space(3))) unsigned int*)(unsigned)(unsigned long long)lds_uniform_base,
        16, 0, 0);
}

#define BARRIER __builtin_amdgcn_s_barrier()
#define WAIT_LGKM0 asm volatile("s_waitcnt lgkmcnt(0)")
#define WAIT_LGKM8 asm volatile("s_waitcnt lgkmcnt(8)")
#define WAIT_VM(n) asm volatile("s_waitcnt vmcnt(" #n ")")

__global__ void cvt_x(const float* __restrict__ x, unsigned short* __restrict__ xb) {
    int i = blockIdx.x * 256 + threadIdx.x;
    float4 v = ((const float4*)x)[i];
    ushort4 o;
    o.x = f2b(v.x); o.y = f2b(v.y); o.z = f2b(v.z); o.w = f2b(v.w);
    ((ushort4*)xb)[i] = o;
}

__global__ void transpose_w(const float* __restrict__ w0, const float* __restrict__ w1,
                            const float* __restrict__ w2, unsigned short* __restrict__ wt) {
    const float* W = (blockIdx.z == 0) ? w0 : (blockIdx.z == 1) ? w1 : w2;
    __shared__ float t[32][33];
    int k0 = blockIdx.y * 32, n0 = blockIdx.x * 32;
    int tx = threadIdx.x, ty = threadIdx.y; // (32,8)
#pragma unroll
    for (int i = 0; i < 4; i++)
        t[ty * 4 + i][tx] = W[(size_t)(k0 + ty * 4 + i) * 1024 + n0 + tx];
    __syncthreads();
    unsigned short* out = wt + (size_t)blockIdx.z * 1024 * 1024;
#pragma unroll
    for (int i = 0; i < 4; i++)
        out[(size_t)(n0 + ty * 4 + i) * 1024 + k0 + tx] = f2b(t[tx][ty * 4 + i]);
}

// ---------------------------------------------------------------------------
// 8-phase 256x256 NT GEMM (phase ledger verified round 5; unchanged).
// LDS layout: [2 buf][4 chunks of 64 rows][row: 8 x 16B slots], linear for
// global_load_lds. SWIZZLE (involution, both sides): LDS slot j of row r holds
// global 16B-chunk j ^ (r&7).
//   write side: thread (row=tid>>3, slot=tid&7) fetches global chunk (tid&7)^(row&7)
//   read side : wanted chunk g=ks*4+(lane>>4) read at slot g^(row&7), row&7==l16&7
// Bank effect: per 16-lane group all 8 slots hit -> 32 banks, 2-way (free).
// MODE 0: bf16 [m][n] +z*sC. MODE 2: fp32. MODE 3: fused proj (N=3072 -> kb,qb,vtb^T).
// ---------------------------------------------------------------------------
template <int MODE>
__global__ __launch_bounds__(512, 2) void gemm8(
    const unsigned short* __restrict__ A, const unsigned short* __restrict__ Bm,
    void* __restrict__ C0, void* __restrict__ C1, void* __restrict__ C2,
    const float* __restrict__ bias0, const float* __restrict__ bias1,
    const float* __restrict__ bias2,
    int N, int K, long long sA, long long sB, long long sC, float alpha) {
    __shared__ unsigned short As[2][256 * 64];
    __shared__ unsigned short Bs[2][256 * 64];
    const int tid = threadIdx.x;
    const int wave = tid >> 6, lane = tid & 63;

    // T1 bijective XCD swizzle (m204)
    const int gx = gridDim.x, gy = gridDim.y;
    const int nwg = gx * gy * (int)gridDim.z;
    const int orig = blockIdx.x + gx * (blockIdx.y + gy * blockIdx.z);
    const int q8 = nwg >> 3, r8 = nwg & 7;
    const int xcd = orig & 7, sub = orig >> 3;
    const int wg = (xcd < r8 ? xcd * (q8 + 1) : r8 * (q8 + 1) + (xcd - r8) * q8) + sub;
    const int bx = wg % gx;
    const int tmp = wg / gx;
    const int by = tmp % gy, bz = tmp / gy;

    const int m0 = by * 256, n0 = bx * 256;
    A += (long long)bz * sA;
    Bm += (long long)bz * sB;

    const int wm = wave >> 2, wn = wave & 3; // 2m x 4n waves
    const int l16 = lane & 15;
    const int g0 = lane >> 4;   // 16B-slot group 0..3
    const int lsw = l16 & 7;    // row swizzle key
    const int nt = K >> 6;      // 64-wide K tiles (nt even, >= 4)

    f32x4 acc[8][4];
#pragma unroll
    for (int m = 0; m < 8; m++)
#pragma unroll
        for (int n = 0; n < 4; n++) acc[m][n] = (f32x4){0.f, 0.f, 0.f, 0.f};

    const int strow = tid >> 3;                          // staging row within chunk
    const int stkk = ((tid & 7) ^ (strow & 7)) << 3;     // inverse-swizzled source chunk

    auto ST_A = [&](int bb, int c, int tt) {
        if (tt >= nt) return;
        gload16(A + (size_t)(m0 + c * 64 + strow) * K + (tt << 6) + stkk,
                (char*)&As[bb][0] + c * 8192 + wave * 1024);
    };
    auto ST_B = [&](int bb, int c, int tt) {
        if (tt >= nt) return;
        gload16(Bm + (size_t)(n0 + c * 64 + strow) * K + (tt << 6) + stkk,
                (char*)&Bs[bb][0] + c * 8192 + wave * 1024);
    };

    short8 af[4][2], bf0[2][2], bf1[2][2];
    auto DS_A = [&](int bb, int mh) { // 8 ds_read_b128, swizzled slots
#pragma unroll
        for (int fm = 0; fm < 4; fm++)
#pragma unroll
            for (int ks = 0; ks < 2; ks++)
                af[fm][ks] = *(const short8*)
                    &As[bb][(wm * 128 + mh * 64 + fm * 16 + l16) * 64 +
                            ((((ks << 2) + g0) ^ lsw) << 3)];
    };
    auto DS_B = [&](int bb, int nh, short8 (&bf)[2][2]) { // 4 ds_read_b128
#pragma unroll
        for (int fn = 0; fn < 2; fn++)
#pragma unroll
            for (int ks = 0; ks < 2; ks++)
                bf[fn][ks] = *(const short8*)
                    &Bs[bb][(wn * 64 + nh * 32 + fn * 16 + l16) * 64 +
                            ((((ks << 2) + g0) ^ lsw) << 3)];
    };
    auto MFMA16 = [&](int mh, int nh, short8 (&bf)[2][2]) {
        __builtin_amdgcn_s_setprio(1);
#pragma unroll
        for (int fm = 0; fm < 4; fm++)
#pragma unroll
            for (int fn = 0; fn < 2; fn++)
#pragma unroll
                for (int ks = 0; ks < 2; ks++)
                    acc[mh * 4 + fm][nh * 2 + fn] = __builtin_amdgcn_mfma_f32_16x16x32_bf16(
                        af[fm][ks], bf[fn][ks], acc[mh * 4 + fm][nh * 2 + fn], 0, 0, 0);
        __builtin_amdgcn_s_setprio(0);
    };

    // prologue: tile0 full (8 loads), tile1 partial (6); tile1 Bs c2,c3 staged at ph1
    ST_A(0, 0, 0); ST_A(0, 1, 0); ST_A(0, 2, 0); ST_A(0, 3, 0);
    ST_B(0, 0, 0); ST_B(0, 1, 0); ST_B(0, 2, 0); ST_B(0, 3, 0);
    ST_A(1, 0, 1); ST_A(1, 1, 1); ST_A(1, 2, 1); ST_A(1, 3, 1);
    ST_B(1, 0, 1); ST_B(1, 1, 1);
    WAIT_VM(6); // drain tile0's 8 (oldest), leave tile1's 6 in flight
    BARRIER;

    for (int it = 0; it < (nt >> 1); ++it) {
        const int t = it << 1;
        const bool last = (t + 2 >= nt);
        // ph1 (12 ds_reads)
        DS_A(0, 0); DS_B(0, 0, bf0);
        ST_B(1, 2, t + 1); ST_B(1, 3, t + 1);
        WAIT_LGKM8;
        BARRIER; WAIT_LGKM0;
        MFMA16(0, 0, bf0);
        BARRIER;
        // ph2
        DS_B(0, 1, bf1);
        ST_A(0, 0, t + 2); ST_A(0, 2, t + 2);
        BARRIER; WAIT_LGKM0;
        MFMA16(0, 1, bf1);
        BARRIER;
        // ph3
        DS_A(0, 1);
        ST_B(0, 0, t + 2); ST_B(0, 1, t + 2);
        BARRIER; WAIT_LGKM0;
        MFMA16(1, 0, bf0);
        BARRIER;
        // ph4 (counted vmcnt releases ph5's reads of tile t+1)
        ST_A(0, 1, t + 2); ST_A(0, 3, t + 2);
        BARRIER;
        MFMA16(1, 1, bf1);
        if (last) { WAIT_VM(0); } else { WAIT_VM(6); }
        BARRIER;
        // ph5 (12 ds_reads)
        DS_A(1, 0); DS_B(1, 0, bf0);
        ST_B(0, 2, t + 2); ST_B(0, 3, t + 2);
        WAIT_LGKM8;
        BARRIER; WAIT_LGKM0;
        MFMA16(0, 0, bf0);
        BARRIER;
        // ph6
        DS_B(1, 1, bf1);
        ST_A(1, 0, t + 3); ST_A(1, 2, t + 3);
        BARRIER; WAIT_LGKM0;
        MFMA16(0, 1, bf1);
        BARRIER;
        // ph7
        DS_A(1, 1);
        ST_B(1, 0, t + 3); ST_B(1, 1, t + 3);
        BARRIER; WAIT_LGKM0;
        MFMA16(1, 0, bf0);
        BARRIER;
        // ph8 (counted vmcnt releases next ph1's reads of tile t+2)
        ST_A(1, 1, t + 3); ST_A(1, 3, t + 3);
        BARRIER;
        MFMA16(1, 1, bf1);
        if (last) { WAIT_VM(0); } else { WAIT_VM(6); }
        BARRIER;
    }

    const int rowb0 = m0 + wm * 128 + ((lane >> 4) << 2);
#pragma unroll
    for (int m = 0; m < 8; m++) {
#pragma unroll
        for (int n = 0; n < 4; n++) {
            const int row = rowb0 + m * 16;
            const int col = n0 + wn * 64 + n * 16 + l16;
            if (MODE == 0) {
                unsigned short* C = (unsigned short*)C0 + (long long)bz * sC;
                float bb = bias0 ? bias0[col] : 0.f;
#pragma unroll
                for (int i = 0; i < 4; i++)
                    C[(size_t)(row + i) * N + col] = f2b(acc[m][n][i] * alpha + bb);
            } else if (MODE == 2) {
                float* C = (float*)C0 + (long long)bz * sC;
                float bb = bias0 ? bias0[col] : 0.f;
#pragma unroll
                for (int i = 0; i < 4; i++)
                    C[(size_t)(row + i) * N + col] = acc[m][n][i] * alpha + bb;
            } else { // MODE 3: fused proj routing
                const int sel = col >> 10, lc = col & 1023;
                const float bb = (sel == 0 ? bias0 : sel == 1 ? bias1 : bias2)[lc];
                if (sel < 2) {
                    unsigned short* C = (unsigned short*)(sel == 0 ? C0 : C1);
#pragma unroll
                    for (int i = 0; i < 4; i++)
                        C[(size_t)(row + i) * 1024 + lc] = f2b(acc[m][n][i] + bb);
                } else {
                    const int b = row >> 11, s = row & 2047;
                    ushort4 pk;
                    pk.x = f2b(acc[m][n][0] + bb);
                    pk.y = f2b(acc[m][n][1] + bb);
                    pk.z = f2b(acc[m][n][2] + bb);
                    pk.w = f2b(acc[m][n][3] + bb);
                    *(ushort4*)((unsigned short*)C2 + (size_t)b * 2097152 +
                                (size_t)lc * 2048 + s) = pk;
                }
            }
        }
    }
}

// 2-phase 256xBN GEMM (round-4 proven) — used for PV. MODE 2: fp32 out.
template <int BN, int MODE>
__global__ __launch_bounds__(512, 2) void gemm2(
    const unsigned short* __restrict__ A, const unsigned short* __restrict__ Bm,
    void* __restrict__ Cv, const float* __restrict__ bias,
    int N, int K, long long sA, long long sB, long long sC, float alpha) {
    constexpr int FN = BN / 64;
    __shared__ unsigned short As[2][256 * 64];
    __shared__ unsigned short Bs[2][BN * 64];
    const int tid = threadIdx.x;
    const int wave = tid >> 6, lane = tid & 63;

    const int gx = gridDim.x, gy = gridDim.y;
    const int nwg = gx * gy * (int)gridDim.z;
    const int orig = blockIdx.x + gx * (blockIdx.y + gy * blockIdx.z);
    const int q8 = nwg >> 3, r8 = nwg & 7;
    const int xcd = orig & 7, sub = orig >> 3;
    const int wg = (xcd < r8 ? xcd * (q8 + 1) : r8 * (q8 + 1) + (xcd - r8) * q8) + sub;
    const int bx = wg % gx;
    const int tmp = wg / gx;
    const int by = tmp % gy, bz = tmp / gy;

    const int m0 = by * 256, n0 = bx * BN;
    A += (long long)bz * sA;
    Bm += (long long)bz * sB;

    const int wm = wave >> 2, wn = wave & 3;
    const int l16 = lane & 15;
    const int lk = (lane >> 4) << 3;

    f32x4 acc[8][FN];
#pragma unroll
    for (int m = 0; m < 8; m++)
#pragma unroll
        for (int n = 0; n < FN; n++) acc[m][n] = (f32x4){0.f, 0.f, 0.f, 0.f};

    auto STAGE = [&](int buf, int t) {
        const int k0 = t << 6;
#pragma unroll
        for (int j = 0; j < 4; j++) {
            int cid = tid + j * 512;
            int row = cid >> 3, kk = (cid & 7) << 3;
            gload16(A + (size_t)(m0 + row) * K + k0 + kk,
                    (char*)&As[buf][0] + wave * 1024 + j * 8192);
        }
#pragma unroll
        for (int j = 0; j < FN; j++) {
            int cid = tid + j * 512;
            int row = cid >> 3, kk = (cid & 7) << 3;
            gload16(Bm + (size_t)(n0 + row) * K + k0 + kk,
                    (char*)&Bs[buf][0] + wave * 1024 + j * 8192);
        }
    };

    const int nt = K >> 6;
    int cur = 0;
    STAGE(0, 0);
    __syncthreads();
    for (int t = 0; t < nt; ++t) {
        if (t + 1 < nt) STAGE(cur ^ 1, t + 1);
#pragma unroll
        for (int ks = 0; ks < 2; ks++) {
            short8 af[8], bf[FN];
#pragma unroll
            for (int m = 0; m < 8; m++)
                af[m] = *(const short8*)&As[cur][(wm * 128 + m * 16 + l16) * 64 + ks * 32 + lk];
#pragma unroll
            for (int n = 0; n < FN; n++)
                bf[n] = *(const short8*)&Bs[cur][(wn * (BN / 4) + n * 16 + l16) * 64 + ks * 32 + lk];
#pragma unroll
            for (int m = 0; m < 8; m++)
#pragma unroll
                for (int n = 0; n < FN; n++)
                    acc[m][n] = __builtin_amdgcn_mfma_f32_16x16x32_bf16(af[m], bf[n], acc[m][n], 0, 0, 0);
        }
        __syncthreads();
        cur ^= 1;
    }

    const int rowb0 = m0 + wm * 128 + ((lane >> 4) << 2);
    const int colb0 = n0 + wn * (BN / 4) + l16;
#pragma unroll
    for (int m = 0; m < 8; m++) {
#pragma unroll
        for (int n = 0; n < FN; n++) {
            int col = colb0 + n * 16;
            int rowb = rowb0 + m * 16;
            float bv_ = bias ? bias[col] : 0.f;
            if (MODE == 2) {
                float* C = (float*)Cv + (long long)bz * sC;
#pragma unroll
                for (int i = 0; i < 4; i++)
                    C[(size_t)(rowb + i) * N + col] = acc[m][n][i] * alpha + bv_;
            } else {
                unsigned short* C = (unsigned short*)Cv + (long long)bz * sC;
#pragma unroll
                for (int i = 0; i < 4; i++)
                    C[(size_t)(rowb + i) * N + col] = f2b(acc[m][n][i] * alpha + bv_);
            }
        }
    }
}

// in-place row softmax: sc bf16 [8192][2048], fp32 math
__global__ __launch_bounds__(256) void softmax_inplace(unsigned short* __restrict__ sc) {
    const size_t row = blockIdx.x;
    unsigned short* p = sc + row * 2048;
    const int tid = threadIdx.x;
    const int wave = tid >> 6, lane = tid & 63;
    short8 raw = *(const short8*)&p[tid * 8];
    float f[8];
#pragma unroll
    for (int i = 0; i < 8; i++) f[i] = b2f((unsigned short)raw[i]);
    float mx = f[0];
#pragma unroll
    for (int i = 1; i < 8; i++) mx = fmaxf(mx, f[i]);
#pragma unroll
    for (int o = 32; o > 0; o >>= 1) mx = fmaxf(mx, __shfl_xor(mx, o, 64));
    __shared__ float red[8];
    if (lane == 0) red[wave] = mx;
    __syncthreads();
    mx = fmaxf(fmaxf(red[0], red[1]), fmaxf(red[2], red[3]));
    float e[8], s = 0.f;
#pragma unroll
    for (int i = 0; i < 8; i++) { e[i] = __expf(f[i] - mx); s += e[i]; }
#pragma unroll
    for (int o = 32; o > 0; o >>= 1) s += __shfl_xor(s, o, 64);
    if (lane == 0) red[4 + wave] = s;
    __syncthreads();
    s = (red[4] + red[5]) + (red[6] + red[7]);
    float r = 1.0f / s;
    short8 outv;
#pragma unroll
    for (int i = 0; i < 8; i++) outv[i] = (short)f2b(e[i] * r);
    *(short8*)&p[tid * 8] = outv;
}

extern "C" void kernel_launch(void* const* d_in, const int* in_sizes, int n_in,
                              void* d_out, int out_size, void* d_ws, size_t ws_size,
                              hipStream_t stream) {
    const float* x  = (const float*)d_in[0];
    const float* Wk = (const float*)d_in[1];
    const float* bk = (const float*)d_in[2];
    const float* Wq = (const float*)d_in[3];
    const float* bq = (const float*)d_in[4];
    const float* Wv = (const float*)d_in[5];
    const float* bv = (const float*)d_in[6];
    float* out = (float*)d_out;

    char* ws = (char*)d_ws;
    unsigned short* xb  = (unsigned short*)(ws);
    unsigned short* wt  = (unsigned short*)(ws + 16777216);
    unsigned short* kb  = (unsigned short*)(ws + 23068672);
    unsigned short* qb  = (unsigned short*)(ws + 39845888);
    unsigned short* vtb = (unsigned short*)(ws + 56623104);
    unsigned short* sc  = (unsigned short*)(ws + 73400320);

    cvt_x<<<8192, 256, 0, stream>>>(x, xb);
    transpose_w<<<dim3(32, 32, 3), dim3(32, 8), 0, stream>>>(Wk, Wq, Wv, wt);

    // fused QKV projection: M=8192, N=3072, K=1024 — grid 12x32 = 384 blocks
    gemm8<3><<<dim3(12, 32, 1), 512, 0, stream>>>(
        xb, wt, kb, qb, vtb, bk, bq, bv, 3072, 1024, 0, 0, 0, 1.f);

    // scores: per batch 2048x2048, K=1024 — grid 8x8x4 = 256 blocks
    gemm8<0><<<dim3(8, 8, 4), 512, 0, stream>>>(
        qb, kb, sc, nullptr, nullptr, nullptr, nullptr, nullptr,
        2048, 1024, 2048LL * 1024, 2048LL * 1024, 2048LL * 2048, 0.03125f);

    softmax_inplace<<<8192, 256, 0, stream>>>(sc);

    // PV: per batch M=2048, N=1024, K=2048 — 2-phase, 256x128 tiles, 256 blocks
    gemm2<128, 2><<<dim3(8, 8, 4), 512, 0, stream>>>(
        sc, vtb, out, nullptr, 1024, 2048,
        2048LL * 2048, 1024LL * 2048, 2048LL * 1024, 1.f);
}